// Round 11
// baseline (174.126 us; speedup 1.0000x reference)
//
#include <hip/hip_runtime.h>

#define B_ 4
#define S_ 512
#define D_ 512
#define H_ 8
#define DK_ 64
#define NREL 41

typedef __attribute__((ext_vector_type(8))) short bf16x8;
typedef __attribute__((ext_vector_type(4))) float f32x4;

__device__ __forceinline__ unsigned short f2bf(float f) {
  unsigned u = __float_as_uint(f);
  u = u + 0x7FFFu + ((u >> 16) & 1u);
  return (unsigned short)(u >> 16);
}

#define MFMA16(a, b, c) __builtin_amdgcn_mfma_f32_16x16x32_bf16((a), (b), (c), 0, 0, 0)

// Wave-local LDS fence: all prior DS ops complete, nothing crosses.
#define LDS_FENCE() do { \
  asm volatile("s_waitcnt lgkmcnt(0)" ::: "memory"); \
  __builtin_amdgcn_sched_barrier(0); \
} while (0)

// ---------------------------------------------------------------------------
// Kernel 1 (prep), grid (8,8,8):
//  z<4 : 64x64 tile transpose W[z] f32[K][N] -> bf16 WT[N][K]
//  z==4: all 64 xy-blocks pack mask int32 -> uint8; block (0,0) also does
//        emb_k -> ekb [48][64] (rows>=41 zero), emb_v -> evt [64][64] (emb_v^T)
//  z>=5: input[z-5] f32 [2048][512] -> bf16 row-major
// ---------------------------------------------------------------------------
struct PrepArgs { const float* W[4]; const float* in[3]; };

__global__ __launch_bounds__(256) void prep(PrepArgs PA,
    const float* __restrict__ embk, const float* __restrict__ embv,
    const int* __restrict__ mask,
    ushort* __restrict__ WT0, ushort* __restrict__ ekb, ushort* __restrict__ evt,
    ushort* __restrict__ inbf0, uchar* __restrict__ mask8)
{
  const int z = blockIdx.z;
  const int t = threadIdx.x;
  if (z == 4) {
    int lb = blockIdx.y * 8 + blockIdx.x;           // 64 blocks
    size_t base = (size_t)lb * 16384;               // 1M ints total
    #pragma unroll
    for (int i = 0; i < 16; ++i) {
      size_t off = base + (size_t)i * 1024 + t * 4;
      int4 v = *(const int4*)&mask[off];
      uchar4 pk;
      pk.x = (uchar)v.x; pk.y = (uchar)v.y; pk.z = (uchar)v.z; pk.w = (uchar)v.w;
      *(uchar4*)&mask8[off] = pk;
    }
    if (lb == 0) {
      for (int i = t; i < 48 * 64; i += 256) {
        int r = i >> 6, d = i & 63;
        ekb[i] = (r < NREL) ? f2bf(embk[r * 64 + d]) : (ushort)0;
      }
      for (int i = t; i < 64 * 64; i += 256) {
        int d = i >> 6, r = i & 63;
        evt[i] = (r < NREL) ? f2bf(embv[r * 64 + d]) : (ushort)0;
      }
    }
    return;
  }
  if (z >= 5) {
    const float* src = PA.in[z - 5];
    ushort* dst = inbf0 + (size_t)(z - 5) * ((size_t)2048 * 512);
    int lb = blockIdx.y * 8 + blockIdx.x;           // 64 blocks
    size_t base = (size_t)lb * 16384;
    #pragma unroll
    for (int i = 0; i < 16; ++i) {
      size_t off = base + (size_t)i * 1024 + t * 4;
      float4 v = *(const float4*)&src[off];
      ushort4 pk;
      pk.x = f2bf(v.x); pk.y = f2bf(v.y); pk.z = f2bf(v.z); pk.w = f2bf(v.w);
      *(ushort4*)&dst[off] = pk;
    }
    return;
  }
  __shared__ float sh[64][65];
  const float* W = PA.W[z];
  ushort* WT = WT0 + (size_t)z * (D_ * D_);
  const int k0 = blockIdx.x * 64, n0 = blockIdx.y * 64;
  const int rr = t >> 4, cc = (t & 15) * 4;
  #pragma unroll
  for (int i = 0; i < 4; ++i) {
    float4 v = *(const float4*)&W[(size_t)(k0 + rr + i * 16) * D_ + n0 + cc];
    sh[rr + i * 16][cc + 0] = v.x; sh[rr + i * 16][cc + 1] = v.y;
    sh[rr + i * 16][cc + 2] = v.z; sh[rr + i * 16][cc + 3] = v.w;
  }
  __syncthreads();
  #pragma unroll
  for (int i = 0; i < 4; ++i) {
    int r2 = rr + i * 16;
    ushort4 pk;
    pk.x = f2bf(sh[cc + 0][r2]); pk.y = f2bf(sh[cc + 1][r2]);
    pk.z = f2bf(sh[cc + 2][r2]); pk.w = f2bf(sh[cc + 3][r2]);
    *(ushort4*)&WT[(size_t)(n0 + r2) * D_ + k0 + cc] = pk;
  }
}

// ---------------------------------------------------------------------------
// Kernel 2: bf16 MFMA GEMM, 256 thr = 4 waves (2x2), wave tile 32x32,
// block tile 64x64, BK=64. A bf16 [2048][512]; Wt bf16 [N][K].
// mode 1: bf16 head-major [b][h][s][d], (acc+bias)*oscale
// mode 2: bf16 transposed [b][h][d][s]  (V^T)
// mode 3: f32 partial [m][n] (no bias)  (split-K out GEMM)
// ---------------------------------------------------------------------------
struct GemmP  { const ushort* A; const ushort* Wt; const float* bias; void* out;
                int mode; int kbeg; int kend; float oscale; };
struct GemmPs { GemmP p[3]; };

__global__ __launch_bounds__(256) void gemm_bf16(GemmPs P)
{
  __shared__ ushort As[64][72];
  __shared__ ushort Bs[64][72];
  const GemmP gp = P.p[blockIdx.z];
  const int t = threadIdx.x, l = t & 63, w = t >> 6;
  const int r16 = l & 15, g4 = l >> 4;
  const int wmo = (w >> 1) * 32, wno = (w & 1) * 32;
  const int m0 = blockIdx.x * 64, n0 = blockIdx.y * 64;

  f32x4 acc[2][2];
  #pragma unroll
  for (int mi = 0; mi < 2; ++mi)
    #pragma unroll
    for (int ni = 0; ni < 2; ++ni) acc[mi][ni] = 0.0f;

  const int srow = t >> 2, sseg = (t & 3) * 16;
  for (int k0 = gp.kbeg; k0 < gp.kend; k0 += 64) {
    __syncthreads();
    *(uint4*)&As[srow][sseg]     = *(const uint4*)&gp.A[(size_t)(m0 + srow) * D_ + k0 + sseg];
    *(uint4*)&As[srow][sseg + 8] = *(const uint4*)&gp.A[(size_t)(m0 + srow) * D_ + k0 + sseg + 8];
    *(uint4*)&Bs[srow][sseg]     = *(const uint4*)&gp.Wt[(size_t)(n0 + srow) * D_ + k0 + sseg];
    *(uint4*)&Bs[srow][sseg + 8] = *(const uint4*)&gp.Wt[(size_t)(n0 + srow) * D_ + k0 + sseg + 8];
    __syncthreads();
    #pragma unroll
    for (int kk = 0; kk < 2; ++kk) {
      bf16x8 af[2], bfr[2];
      #pragma unroll
      for (int i = 0; i < 2; ++i) af[i]  = *(const bf16x8*)&As[wmo + i * 16 + r16][kk * 32 + g4 * 8];
      #pragma unroll
      for (int i = 0; i < 2; ++i) bfr[i] = *(const bf16x8*)&Bs[wno + i * 16 + r16][kk * 32 + g4 * 8];
      #pragma unroll
      for (int mi = 0; mi < 2; ++mi)
        #pragma unroll
        for (int ni = 0; ni < 2; ++ni)
          acc[mi][ni] = MFMA16(af[mi], bfr[ni], acc[mi][ni]);
    }
  }

  // epilogue (C/D map: col = l&15, row = (l>>4)*4 + reg)
  #pragma unroll
  for (int mi = 0; mi < 2; ++mi) {
    #pragma unroll
    for (int ni = 0; ni < 2; ++ni) {
      int n = n0 + wno + ni * 16 + r16;
      int mb = m0 + wmo + mi * 16 + g4 * 4;
      if (gp.mode == 3) {
        float* PO = (float*)gp.out;
        #pragma unroll
        for (int r = 0; r < 4; ++r) PO[(size_t)(mb + r) * D_ + n] = acc[mi][ni][r];
      } else {
        float bv = gp.bias[n];
        ushort* O = (ushort*)gp.out;
        int h = n >> 6, d = n & 63;
        if (gp.mode == 1) {
          #pragma unroll
          for (int r = 0; r < 4; ++r) {
            int m = mb + r, b = m >> 9, s = m & 511;
            O[(((size_t)(b * H_ + h)) * S_ + s) * DK_ + d] = f2bf((acc[mi][ni][r] + bv) * gp.oscale);
          }
        } else {
          int b = mb >> 9, s = mb & 511;
          ushort4 pk;
          pk.x = f2bf(acc[mi][ni][0] + bv); pk.y = f2bf(acc[mi][ni][1] + bv);
          pk.z = f2bf(acc[mi][ni][2] + bv); pk.w = f2bf(acc[mi][ni][3] + bv);
          *(ushort4*)&O[(((size_t)(b * H_ + h)) * DK_ + d) * S_ + s] = pk;
        }
      }
    }
  }
}

// ---------------------------------------------------------------------------
// Kernel 3: fused attention, split-K x2, 512 blocks x 4 waves.
// Block g: (h=g&7 -> XCD affinity, b, chunk=1bit, qtg); wave w: q-tile qtg*4+w.
// K/V double-buffered in LDS, reg-staged with async split (issue loads early,
// ds_write late), XOR-swizzled LDS (slot = c16 ^ (row&7)) to kill the
// 16-way bank conflict of 128B-stride rows. Mask tile staged once.
// qrel/wr/Pb stay wave-private. One __syncthreads per kt tile.
// ---------------------------------------------------------------------------
__global__ __launch_bounds__(256) void attn_mfma(
    const ushort* __restrict__ qb,  // [B][H][S][64] bf16 (Q pre-scaled 1/8)
    const ushort* __restrict__ kb,  // [B][H][S][64] bf16
    const ushort* __restrict__ vtb, // [B][H][64][S] bf16 (V^T)
    const uchar* __restrict__ mask8,
    const ushort* __restrict__ ekb, // [48][64] bf16
    const ushort* __restrict__ evt, // [64][64] bf16
    float* __restrict__ part,       // [2][B][S][D] f32
    float* __restrict__ sums)       // [2][32][512] f32
{
  __shared__ ushort Kbuf[2][4096];      // 16 KB  [row 0..63][swz slot*8]
  __shared__ ushort Vbuf[2][4096];      // 16 KB
  __shared__ uchar  maskT[64 * 256];    // 16 KB  [qrow][kcol in chunk]
  __shared__ float  qrelS[4][16][48];   // 12 KB
  __shared__ float  wrS[4][16][44];     // 11 KB
  __shared__ ushort PbS[4][16][72];     // 9 KB
  const int t = threadIdx.x, w = t >> 6, l = t & 63;
  const int g = blockIdx.x;
  const int h = g & 7, b = (g >> 3) & 3, chunk = (g >> 5) & 1, qtg = g >> 6;
  const int qt = qtg * 4 + w;
  const int bh = b * H_ + h;
  const int r16 = l & 15, g4 = l >> 4;
  float  (*qrel)[48] = qrelS[w];
  float  (*wr)[44]   = wrS[w];
  ushort (*Pb)[72]   = PbS[w];
  const int kt0 = chunk * 4;
  const int u0 = t, u1 = t + 256;       // staging unit ids (16B units)
  const int kr0 = u0 >> 3, kc0 = u0 & 7, kr1 = u1 >> 3, kc1 = u1 & 7;
  const int ks0 = (kc0 ^ (kr0 & 7)) * 8, ks1 = (kc1 ^ (kr1 & 7)) * 8;

  // ---- prologue: issue mask + K/V[kt0] loads, then qrel work ----
  const uchar* msrc = mask8 + ((size_t)(b * S_ + qtg * 64)) * S_ + chunk * 256;
  uint4 mreg[4];
  #pragma unroll
  for (int i = 0; i < 4; ++i) {
    int unit = t + i * 256;             // 1024 units of 16B
    mreg[i] = *(const uint4*)&msrc[(size_t)(unit >> 4) * S_ + (unit & 15) * 16];
  }
  const ushort* ksrc = kb + ((size_t)bh * S_ + kt0 * 64) * DK_;
  const ushort* vsrc = vtb + (size_t)bh * DK_ * S_ + kt0 * 64;
  uint4 kreg0 = *(const uint4*)&ksrc[kr0 * 64 + kc0 * 8];
  uint4 kreg1 = *(const uint4*)&ksrc[kr1 * 64 + kc1 * 8];
  uint4 vreg0 = *(const uint4*)&vsrc[(size_t)kr0 * S_ + kc0 * 8];
  uint4 vreg1 = *(const uint4*)&vsrc[(size_t)kr1 * S_ + kc1 * 8];
  __builtin_amdgcn_sched_barrier(0);    // pin the issues above

  { // zero histogram bins (wave-private)
    float* wrf = &wr[0][0];
    #pragma unroll
    for (int i = 0; i < 11; ++i) wrf[i * 64 + l] = 0.f;
  }

  const size_t qoff = ((size_t)bh * S_ + qt * 16) * DK_;
  bf16x8 qf0 = *(const bf16x8*)&qb[qoff + (size_t)r16 * DK_ + g4 * 8];
  bf16x8 qf1 = *(const bf16x8*)&qb[qoff + (size_t)r16 * DK_ + 32 + g4 * 8];

  { // qrel[q][r] = q . emb_k[r] (scaled, since q is pre-scaled)
    #pragma unroll
    for (int s = 0; s < 3; ++s) {
      bf16x8 e0 = *(const bf16x8*)&ekb[(s * 16 + r16) * 64 + g4 * 8];
      bf16x8 e1 = *(const bf16x8*)&ekb[(s * 16 + r16) * 64 + 32 + g4 * 8];
      f32x4 qr = 0.0f;
      qr = MFMA16(qf0, e0, qr);
      qr = MFMA16(qf1, e1, qr);
      #pragma unroll
      for (int r = 0; r < 4; ++r) qrel[g4 * 4 + r][s * 16 + r16] = qr[r];
    }
  }

  // write staged tiles (compiler inserts the vmcnt wait here, once)
  #pragma unroll
  for (int i = 0; i < 4; ++i) {
    int unit = t + i * 256;
    *(uint4*)&maskT[unit * 16] = mreg[i];
  }
  *(uint4*)&Kbuf[0][kr0 * 64 + ks0] = kreg0;
  *(uint4*)&Kbuf[0][kr1 * 64 + ks1] = kreg1;
  *(uint4*)&Vbuf[0][kr0 * 64 + ks0] = vreg0;
  *(uint4*)&Vbuf[0][kr1 * 64 + ks1] = vreg1;
  __syncthreads();

  float ssum[4] = {0.f, 0.f, 0.f, 0.f};
  f32x4 oacc[4];
  #pragma unroll
  for (int i = 0; i < 4; ++i) oacc[i] = 0.0f;

  #pragma unroll
  for (int kti = 0; kti < 4; ++kti) {
    const int cur = kti & 1;
    // issue next tile's loads (in flight across this tile's compute)
    if (kti < 3) {
      const ushort* kn = kb + ((size_t)bh * S_ + (kt0 + kti + 1) * 64) * DK_;
      const ushort* vn = vtb + (size_t)bh * DK_ * S_ + (kt0 + kti + 1) * 64;
      kreg0 = *(const uint4*)&kn[kr0 * 64 + kc0 * 8];
      kreg1 = *(const uint4*)&kn[kr1 * 64 + kc1 * 8];
      vreg0 = *(const uint4*)&vn[(size_t)kr0 * S_ + kc0 * 8];
      vreg1 = *(const uint4*)&vn[(size_t)kr1 * S_ + kc1 * 8];
      __builtin_amdgcn_sched_barrier(0);   // don't sink the issues
    }
    // QK^T from swizzled LDS
    f32x4 sacc[4];
    #pragma unroll
    for (int sub = 0; sub < 4; ++sub) {
      int krow = sub * 16 + r16;
      bf16x8 kf0 = *(const bf16x8*)&Kbuf[cur][krow * 64 + ((g4 ^ (krow & 7)) * 8)];
      bf16x8 kf1 = *(const bf16x8*)&Kbuf[cur][krow * 64 + (((g4 + 4) ^ (krow & 7)) * 8)];
      f32x4 z = 0.0f;
      z = MFMA16(qf0, kf0, z);
      z = MFMA16(qf1, kf1, z);
      sacc[sub] = z;
    }
    // mask from LDS (batched, independent)
    int mv[16];
    #pragma unroll
    for (int sub = 0; sub < 4; ++sub)
      #pragma unroll
      for (int r = 0; r < 4; ++r)
        mv[sub * 4 + r] = maskT[(w * 16 + g4 * 4 + r) * 256 + kti * 64 + sub * 16 + r16];
    float qv[16];
    #pragma unroll
    for (int i = 0; i < 16; ++i) qv[i] = qrel[g4 * 4 + (i & 3)][mv[i]];
    // exp + row-sum + histogram + P staging
    #pragma unroll
    for (int sub = 0; sub < 4; ++sub) {
      #pragma unroll
      for (int r = 0; r < 4; ++r) {
        int i = sub * 4 + r;
        float e = (mv[i] > 0) ? __expf(sacc[sub][r] + qv[i]) : 0.f;
        ssum[r] += e;
        atomicAdd(&wr[g4 * 4 + r][mv[i]], e);
        Pb[g4 * 4 + r][sub * 16 + r16] = f2bf(e);
      }
    }
    LDS_FENCE();                       // P writes visible (wave-local)
    bf16x8 pf0 = *(const bf16x8*)&Pb[r16][g4 * 8];
    bf16x8 pf1 = *(const bf16x8*)&Pb[r16][32 + g4 * 8];
    LDS_FENCE();                       // P reads landed before Pb reuse
    // PV from swizzled LDS
    #pragma unroll
    for (int ds = 0; ds < 4; ++ds) {
      int vrow = ds * 16 + r16;
      bf16x8 vf0 = *(const bf16x8*)&Vbuf[cur][vrow * 64 + ((g4 ^ (vrow & 7)) * 8)];
      bf16x8 vf1 = *(const bf16x8*)&Vbuf[cur][vrow * 64 + (((g4 + 4) ^ (vrow & 7)) * 8)];
      oacc[ds] = MFMA16(pf0, vf0, oacc[ds]);
      oacc[ds] = MFMA16(pf1, vf1, oacc[ds]);
    }
    // write staged regs for next tile (vmcnt wait lands here), then barrier
    if (kti < 3) {
      *(uint4*)&Kbuf[cur ^ 1][kr0 * 64 + ks0] = kreg0;
      *(uint4*)&Kbuf[cur ^ 1][kr1 * 64 + ks1] = kreg1;
      *(uint4*)&Vbuf[cur ^ 1][kr0 * 64 + ks0] = vreg0;
      *(uint4*)&Vbuf[cur ^ 1][kr1 * 64 + ks1] = vreg1;
    }
    __syncthreads();
  }

  // O += w @ emb_v   (k-dim = 64 bins, >=41 zero)
  #pragma unroll
  for (int i = 0; i < 16; ++i) {
    int col = g4 * 16 + i;
    Pb[r16][col] = (col < 44) ? f2bf(wr[r16][col]) : (ushort)0;
  }
  LDS_FENCE();
  {
    bf16x8 wf0 = *(const bf16x8*)&Pb[r16][g4 * 8];
    bf16x8 wf1 = *(const bf16x8*)&Pb[r16][32 + g4 * 8];
    #pragma unroll
    for (int ds = 0; ds < 4; ++ds) {
      bf16x8 e0 = *(const bf16x8*)&evt[(ds * 16 + r16) * 64 + g4 * 8];
      bf16x8 e1 = *(const bf16x8*)&evt[(ds * 16 + r16) * 64 + 32 + g4 * 8];
      oacc[ds] = MFMA16(wf0, e0, oacc[ds]);
      oacc[ds] = MFMA16(wf1, e1, oacc[ds]);
    }
  }

  #pragma unroll
  for (int m = 1; m < 16; m <<= 1)
    #pragma unroll
    for (int r = 0; r < 4; ++r) ssum[r] += __shfl_xor(ssum[r], m);

  #pragma unroll
  for (int r = 0; r < 4; ++r) {
    int q = qt * 16 + g4 * 4 + r;
    float* dst = part + (((size_t)chunk * B_ + b) * S_ + q) * D_ + h * DK_;
    #pragma unroll
    for (int ds = 0; ds < 4; ++ds) dst[ds * 16 + r16] = oacc[ds][r];
  }
  if (r16 == 0) {
    size_t sb = ((size_t)chunk * 32 + bh) * S_ + qt * 16 + g4 * 4;
    sums[sb + 0] = ssum[0]; sums[sb + 1] = ssum[1];
    sums[sb + 2] = ssum[2]; sums[sb + 3] = ssum[3];
  }
}

// ---------------------------------------------------------------------------
// Kernel 4: combine 2 attn chunks, normalize, emit bf16 ctx [B][S][D].
// ---------------------------------------------------------------------------
__global__ __launch_bounds__(256) void attn_reduce(
    const float* __restrict__ part, const float* __restrict__ sums,
    ushort* __restrict__ ctx)
{
  int idx = blockIdx.x * 256 + threadIdx.x;
  int d4 = idx & 127;
  int s  = (idx >> 7) & 511;
  int b  = idx >> 16;
  int h  = d4 >> 4;
  float sm = 0.f;
  #pragma unroll
  for (int c = 0; c < 2; ++c) sm += sums[((size_t)c * 32 + b * 8 + h) * S_ + s];
  float inv = 1.f / sm;
  float4 o = make_float4(0.f, 0.f, 0.f, 0.f);
  #pragma unroll
  for (int c = 0; c < 2; ++c) {
    float4 p = *(const float4*)&part[(((size_t)c * B_ + b) * S_ + s) * D_ + d4 * 4];
    o.x += p.x; o.y += p.y; o.z += p.z; o.w += p.w;
  }
  ushort4 pk;
  pk.x = f2bf(o.x * inv); pk.y = f2bf(o.y * inv);
  pk.z = f2bf(o.z * inv); pk.w = f2bf(o.w * inv);
  *(ushort4*)&ctx[((size_t)b * S_ + s) * D_ + d4 * 4] = pk;
}

// ---------------------------------------------------------------------------
// Kernel 5: combine 2 out-GEMM K-chunks + bias -> f32 out [2048][512].
// ---------------------------------------------------------------------------
__global__ __launch_bounds__(256) void out_reduce(
    const float* __restrict__ po, const float* __restrict__ bo,
    float* __restrict__ out)
{
  int idx = blockIdx.x * 256 + threadIdx.x;
  int n4 = (idx & 127) * 4;
  size_t off = (size_t)idx * 4;
  float4 a = *(const float4*)&po[off];
  float4 c = *(const float4*)&po[off + (size_t)2048 * 512];
  float4 bb = *(const float4*)&bo[n4];
  float4 o = make_float4(a.x + c.x + bb.x, a.y + c.y + bb.y,
                         a.z + c.z + bb.z, a.w + c.w + bb.w);
  *(float4*)&out[off] = o;
}

// ---------------------------------------------------------------------------
extern "C" void kernel_launch(void* const* d_in, const int* in_sizes, int n_in,
                              void* d_out, int out_size, void* d_ws, size_t ws_size,
                              hipStream_t stream) {
  (void)in_sizes; (void)n_in; (void)out_size; (void)ws_size;
  const float* query = (const float*)d_in[0];
  const float* key   = (const float*)d_in[1];
  const float* value = (const float*)d_in[2];
  const int*   mask  = (const int*)d_in[3];
  const float* Wq = (const float*)d_in[4];
  const float* bq = (const float*)d_in[5];
  const float* Wk = (const float*)d_in[6];
  const float* bk = (const float*)d_in[7];
  const float* Wv = (const float*)d_in[8];
  const float* bv = (const float*)d_in[9];
  const float* Wo = (const float*)d_in[10];
  const float* bo = (const float*)d_in[11];
  const float* embk = (const float*)d_in[12];
  const float* embv = (const float*)d_in[13];
  float* out = (float*)d_out;

  const size_t MD  = (size_t)2048 * 512;
  const size_t WSZ = (size_t)D_ * D_;
  ushort* wsu  = (ushort*)d_ws;
  ushort* WT   = wsu;                          // 4*WSZ ush
  ushort* ekb  = WT + 4 * WSZ;                 // 3072
  ushort* evt  = ekb + 3072;                   // 4096
  ushort* qbf  = evt + 4096;
  ushort* kbf  = qbf + MD;
  ushort* vtbf = kbf + MD;
  ushort* ctx  = vtbf + MD;
  ushort* inbf = ctx + MD;                     // 3*MD
  float*  sums = (float*)(inbf + 3 * MD);      // 2*32*512 f32 (region sized 4x)
  float*  part = sums + (size_t)4 * 32 * 512;  // 2*MD f32 used (region 4*MD)
  float*  po   = part;                         // alias: out-GEMM partials
  uchar*  mask8 = (uchar*)(part + 4 * MD);     // 1 MB

  PrepArgs PA;
  PA.W[0] = Wq; PA.W[1] = Wk; PA.W[2] = Wv; PA.W[3] = Wo;
  PA.in[0] = query; PA.in[1] = key; PA.in[2] = value;
  prep<<<dim3(8, 8, 8), 256, 0, stream>>>(PA, embk, embv, mask, WT, ekb, evt, inbf, mask8);

  GemmPs P1;
  P1.p[0] = { inbf,          WT + 0 * WSZ, bq, qbf,  1, 0, 512, 0.125f };
  P1.p[1] = { inbf + MD,     WT + 1 * WSZ, bk, kbf,  1, 0, 512, 1.0f };
  P1.p[2] = { inbf + 2 * MD, WT + 2 * WSZ, bv, vtbf, 2, 0, 512, 1.0f };
  gemm_bf16<<<dim3(32, 8, 3), 256, 0, stream>>>(P1);

  attn_mfma<<<dim3(512), 256, 0, stream>>>(qbf, kbf, vtbf, mask8, ekb, evt, part, sums);
  attn_reduce<<<dim3(1024), 256, 0, stream>>>(part, sums, ctx);

  GemmPs P2;
  P2.p[0] = { ctx, WT + 3 * WSZ, nullptr, po,      3, 0,   256, 1.0f };
  P2.p[1] = { ctx, WT + 3 * WSZ, nullptr, po + MD, 3, 256, 512, 1.0f };
  P2.p[2] = P2.p[0];
  gemm_bf16<<<dim3(32, 8, 2), 256, 0, stream>>>(P2);

  out_reduce<<<dim3(1024), 256, 0, stream>>>(po, bo, out);
}